// Round 3
// baseline (583.545 us; speedup 1.0000x reference)
//
#include <hip/hip_runtime.h>

// ---------------------------------------------------------------------------
// GraphConv (DGL norm='both') + residual linear:
//   out = (D_dst^-1/2 * A^T * (D_src^-1/2 * x)) @ W + x @ Wr + (b + br)
// Round 3: prescaled x, high-occupancy unrolled gather (no LDS), separate
// register-blocked GEMM epilogue.
// ---------------------------------------------------------------------------

__global__ void hist_kernel(const int* __restrict__ src, const int* __restrict__ dst,
                            int* __restrict__ cs, int* __restrict__ cd, int e) {
    int i = blockIdx.x * blockDim.x + threadIdx.x;
    int e4 = e >> 2;
    if (i < e4) {
        int4 s = ((const int4*)src)[i];
        int4 d = ((const int4*)dst)[i];
        atomicAdd(&cs[s.x], 1); atomicAdd(&cs[s.y], 1);
        atomicAdd(&cs[s.z], 1); atomicAdd(&cs[s.w], 1);
        atomicAdd(&cd[d.x], 1); atomicAdd(&cd[d.y], 1);
        atomicAdd(&cd[d.z], 1); atomicAdd(&cd[d.w], 1);
    }
    // tail (e not divisible by 4)
    int tail = e & 3;
    if (i < tail) {
        int j = (e & ~3) + i;
        atomicAdd(&cs[src[j]], 1);
        atomicAdd(&cd[dst[j]], 1);
    }
}

// Scan phase A: per-block (256-wide) partial sums of cd.
__global__ void partial_kernel(const int* __restrict__ cnt, int* __restrict__ part, int n) {
    __shared__ int sm[256];
    int i = blockIdx.x * 256 + threadIdx.x;
    sm[threadIdx.x] = (i < n) ? cnt[i] : 0;
    __syncthreads();
    for (int s = 128; s > 0; s >>= 1) {
        if (threadIdx.x < s) sm[threadIdx.x] += sm[threadIdx.x + s];
        __syncthreads();
    }
    if (threadIdx.x == 0) part[blockIdx.x] = sm[0];
}

// Scan phase B: single-block exclusive scan of the partials (nb <= 256).
__global__ void scan_part_kernel(int* __restrict__ part, int nb) {
    __shared__ int sm[256];
    int t = threadIdx.x;
    int v = (t < nb) ? part[t] : 0;
    sm[t] = v;
    __syncthreads();
    for (int d = 1; d < 256; d <<= 1) {
        int add = (t >= d) ? sm[t - d] : 0;
        __syncthreads();
        sm[t] += add;
        __syncthreads();
    }
    if (t < nb) part[t] = sm[t] - v;   // exclusive
}

// Scan phase C: local exclusive scan + block offset -> cursor (= excl prefix).
__global__ void scan_final_kernel(const int* __restrict__ cnt, const int* __restrict__ part,
                                  int* __restrict__ curs, int n) {
    __shared__ int sm[256];
    int t = threadIdx.x;
    int i = blockIdx.x * 256 + t;
    int v = (i < n) ? cnt[i] : 0;
    sm[t] = v;
    __syncthreads();
    for (int d = 1; d < 256; d <<= 1) {
        int add = (t >= d) ? sm[t - d] : 0;
        __syncthreads();
        sm[t] += add;
        __syncthreads();
    }
    if (i < n) curs[i] = sm[t] - v + part[blockIdx.x];
}

// Scatter edge sources into CSR col array. After this, curs[i] = row-end of i
// (inclusive prefix), so row i spans [curs[i-1], curs[i]).
__global__ void scatter_kernel(const int* __restrict__ src, const int* __restrict__ dst,
                               int* __restrict__ curs, int* __restrict__ col, int e) {
    int i = blockIdx.x * blockDim.x + threadIdx.x;
    if (i < e) {
        int p = atomicAdd(&curs[dst[i]], 1);
        col[p] = src[i];
    }
}

// xs = x * rsqrt(max(out_deg,1)), float4-vectorized.
__global__ void prescale_kernel(const float4* __restrict__ x4, const int* __restrict__ cs,
                                float4* __restrict__ xs4, int n16) {
    int i = blockIdx.x * blockDim.x + threadIdx.x;
    if (i < n16) {
        float s = rsqrtf((float)max(cs[i >> 4], 1));
        float4 v = x4[i];
        v.x *= s; v.y *= s; v.z *= s; v.w *= s;
        xs4[i] = v;
    }
}

// One wave per node (lane = feature), no LDS, 8-edge unroll.
// agg[node] = rsqrt(max(in_deg,1)) * sum_{s in N(node)} xs[s]
__global__ __launch_bounds__(256) void gather_kernel(
    const float* __restrict__ xs, const int* __restrict__ col,
    const int* __restrict__ curs, const int* __restrict__ cd,
    float* __restrict__ agg, int n) {
    int lane = threadIdx.x & 63;
    int node = (blockIdx.x * 256 + threadIdx.x) >> 6;
    if (node >= n) return;
    node = __builtin_amdgcn_readfirstlane(node);   // wave-uniform -> scalar loads

    int beg = (node > 0) ? curs[node - 1] : 0;
    int end = curs[node];

    float acc = 0.0f;
    int j = beg;
    for (; j + 8 <= end; j += 8) {
        int s0 = col[j + 0], s1 = col[j + 1], s2 = col[j + 2], s3 = col[j + 3];
        int s4 = col[j + 4], s5 = col[j + 5], s6 = col[j + 6], s7 = col[j + 7];
        float v0 = xs[(long)s0 * 64 + lane];
        float v1 = xs[(long)s1 * 64 + lane];
        float v2 = xs[(long)s2 * 64 + lane];
        float v3 = xs[(long)s3 * 64 + lane];
        float v4 = xs[(long)s4 * 64 + lane];
        float v5 = xs[(long)s5 * 64 + lane];
        float v6 = xs[(long)s6 * 64 + lane];
        float v7 = xs[(long)s7 * 64 + lane];
        acc += ((v0 + v1) + (v2 + v3)) + ((v4 + v5) + (v6 + v7));
    }
    for (; j < end; ++j) acc += xs[(long)col[j] * 64 + lane];

    float nd = rsqrtf((float)max(cd[node], 1));
    agg[(long)node * 64 + lane] = acc * nd;
}

// out[r][c] = agg[r][:]@W[:,c] + x[r][:]@Wr[:,c] + (b+br)[c]
// 32 rows/block, 256 threads, 8 rows x 1 col per thread.
#define GR 32
__global__ __launch_bounds__(256) void gemm_kernel(
    const float* __restrict__ agg, const float* __restrict__ x,
    const float* __restrict__ W, const float* __restrict__ Wr,
    const float* __restrict__ b, const float* __restrict__ br,
    float* __restrict__ out, int n) {
    __shared__ float sA[GR * 64];   // agg tile
    __shared__ float sX[GR * 64];   // x tile
    __shared__ float sW[128 * 64];  // W on top of Wr
    int t = threadIdx.x;
    int base = blockIdx.x * GR;

    for (int i = t; i < 4096; i += 256) {
        sW[i]        = W[i];
        sW[4096 + i] = Wr[i];
    }
    for (int i = t; i < GR * 16; i += 256) {   // float4 chunks
        int row = i >> 4;
        int g = base + row;
        float4 va = make_float4(0.f, 0.f, 0.f, 0.f);
        float4 vx = va;
        if (g < n) {
            va = ((const float4*)agg)[(long)g * 16 + (i & 15)];
            vx = ((const float4*)x)[(long)g * 16 + (i & 15)];
        }
        ((float4*)sA)[i] = va;
        ((float4*)sX)[i] = vx;
    }
    __syncthreads();

    int c = t & 63, rg = t >> 6;
    float acc[8];
    #pragma unroll
    for (int i = 0; i < 8; ++i) acc[i] = 0.f;

    #pragma unroll
    for (int kc = 0; kc < 16; ++kc) {
        float4 a[8];
        #pragma unroll
        for (int i = 0; i < 8; ++i) a[i] = ((const float4*)sA)[(rg * 8 + i) * 16 + kc];
        #pragma unroll
        for (int j = 0; j < 4; ++j) {
            float wv = sW[(kc * 4 + j) * 64 + c];
            #pragma unroll
            for (int i = 0; i < 8; ++i) acc[i] += (&a[i].x)[j] * wv;
        }
    }
    #pragma unroll
    for (int kc = 0; kc < 16; ++kc) {
        float4 a[8];
        #pragma unroll
        for (int i = 0; i < 8; ++i) a[i] = ((const float4*)sX)[(rg * 8 + i) * 16 + kc];
        #pragma unroll
        for (int j = 0; j < 4; ++j) {
            float wv = sW[4096 + (kc * 4 + j) * 64 + c];
            #pragma unroll
            for (int i = 0; i < 8; ++i) acc[i] += (&a[i].x)[j] * wv;
        }
    }

    float bias = b[c] + br[c];
    #pragma unroll
    for (int i = 0; i < 8; ++i) {
        int g = base + rg * 8 + i;
        if (g < n) out[(long)g * 64 + c] = acc[i] + bias;
    }
}

extern "C" void kernel_launch(void* const* d_in, const int* in_sizes, int n_in,
                              void* d_out, int out_size, void* d_ws, size_t ws_size,
                              hipStream_t stream) {
    const float* x   = (const float*)d_in[0];
    const int*   src = (const int*)d_in[1];
    const int*   dst = (const int*)d_in[2];
    const float* W   = (const float*)d_in[3];
    const float* b   = (const float*)d_in[4];
    const float* Wr  = (const float*)d_in[5];
    const float* br  = (const float*)d_in[6];
    float* out = (float*)d_out;

    const int n = in_sizes[0] / 64;   // 50000
    const int e = in_sizes[1];        // 800000
    const int nblk = (n + 255) / 256; // 196

    int*   cs   = (int*)d_ws;          // n
    int*   cd   = cs + n;              // n
    int*   curs = cd + n;              // n
    int*   part = curs + n;            // 256
    int*   col  = part + 256;          // e
    float* xs   = (float*)(col + e);   // n*64
    float* agg  = xs + (size_t)n * 64; // n*64

    hipMemsetAsync(cs, 0, (size_t)n * 2 * sizeof(int), stream);

    hist_kernel<<<(e / 4 + 255) / 256, 256, 0, stream>>>(src, dst, cs, cd, e);

    partial_kernel<<<nblk, 256, 0, stream>>>(cd, part, n);
    scan_part_kernel<<<1, 256, 0, stream>>>(part, nblk);
    scan_final_kernel<<<nblk, 256, 0, stream>>>(cd, part, curs, n);

    scatter_kernel<<<(e + 255) / 256, 256, 0, stream>>>(src, dst, curs, col, e);

    prescale_kernel<<<(n * 16 + 255) / 256, 256, 0, stream>>>(
        (const float4*)x, cs, (float4*)xs, n * 16);

    gather_kernel<<<(n * 64 + 255) / 256, 256, 0, stream>>>(
        xs, col, curs, cd, agg, n);

    gemm_kernel<<<(n + GR - 1) / GR, 256, 0, stream>>>(
        agg, x, W, Wr, b, br, out, n);
}

// Round 4
// 251.383 us; speedup vs baseline: 2.3213x; 2.3213x over previous
//
#include <hip/hip_runtime.h>

// ---------------------------------------------------------------------------
// GraphConv (DGL norm='both') + residual linear:
//   out = (D_dst^-1/2 * A^T * (D_src^-1/2 * x)) @ W + x @ Wr + (b + br)
// Round 4: round-3 pipeline (prescale + unrolled gather) with the proven
// round-2 shuffle epilogue as a standalone kernel (no register-array spills).
// ---------------------------------------------------------------------------

__global__ void hist_kernel(const int* __restrict__ src, const int* __restrict__ dst,
                            int* __restrict__ cs, int* __restrict__ cd, int e) {
    int i = blockIdx.x * blockDim.x + threadIdx.x;
    int e4 = e >> 2;
    if (i < e4) {
        int4 s = ((const int4*)src)[i];
        int4 d = ((const int4*)dst)[i];
        atomicAdd(&cs[s.x], 1); atomicAdd(&cs[s.y], 1);
        atomicAdd(&cs[s.z], 1); atomicAdd(&cs[s.w], 1);
        atomicAdd(&cd[d.x], 1); atomicAdd(&cd[d.y], 1);
        atomicAdd(&cd[d.z], 1); atomicAdd(&cd[d.w], 1);
    }
    int tail = e & 3;
    if (i < tail) {
        int j = (e & ~3) + i;
        atomicAdd(&cs[src[j]], 1);
        atomicAdd(&cd[dst[j]], 1);
    }
}

// Scan phase A: per-block (256-wide) partial sums of cd.
__global__ void partial_kernel(const int* __restrict__ cnt, int* __restrict__ part, int n) {
    __shared__ int sm[256];
    int i = blockIdx.x * 256 + threadIdx.x;
    sm[threadIdx.x] = (i < n) ? cnt[i] : 0;
    __syncthreads();
    for (int s = 128; s > 0; s >>= 1) {
        if (threadIdx.x < s) sm[threadIdx.x] += sm[threadIdx.x + s];
        __syncthreads();
    }
    if (threadIdx.x == 0) part[blockIdx.x] = sm[0];
}

// Scan phase B: single-block exclusive scan of the partials (nb <= 256).
__global__ void scan_part_kernel(int* __restrict__ part, int nb) {
    __shared__ int sm[256];
    int t = threadIdx.x;
    int v = (t < nb) ? part[t] : 0;
    sm[t] = v;
    __syncthreads();
    for (int d = 1; d < 256; d <<= 1) {
        int add = (t >= d) ? sm[t - d] : 0;
        __syncthreads();
        sm[t] += add;
        __syncthreads();
    }
    if (t < nb) part[t] = sm[t] - v;   // exclusive
}

// Scan phase C: local exclusive scan + block offset -> cursor (= excl prefix).
__global__ void scan_final_kernel(const int* __restrict__ cnt, const int* __restrict__ part,
                                  int* __restrict__ curs, int n) {
    __shared__ int sm[256];
    int t = threadIdx.x;
    int i = blockIdx.x * 256 + t;
    int v = (i < n) ? cnt[i] : 0;
    sm[t] = v;
    __syncthreads();
    for (int d = 1; d < 256; d <<= 1) {
        int add = (t >= d) ? sm[t - d] : 0;
        __syncthreads();
        sm[t] += add;
        __syncthreads();
    }
    if (i < n) curs[i] = sm[t] - v + part[blockIdx.x];
}

// Scatter edge sources into CSR col array. After this, curs[i] = row-end of i
// (inclusive prefix), so row i spans [curs[i-1], curs[i]).
__global__ void scatter_kernel(const int* __restrict__ src, const int* __restrict__ dst,
                               int* __restrict__ curs, int* __restrict__ col, int e) {
    int i = blockIdx.x * blockDim.x + threadIdx.x;
    if (i < e) {
        int p = atomicAdd(&curs[dst[i]], 1);
        col[p] = src[i];
    }
}

// xs = x * rsqrt(max(out_deg,1)), float4-vectorized.
__global__ void prescale_kernel(const float4* __restrict__ x4, const int* __restrict__ cs,
                                float4* __restrict__ xs4, int n16) {
    int i = blockIdx.x * blockDim.x + threadIdx.x;
    if (i < n16) {
        float s = rsqrtf((float)max(cs[i >> 4], 1));
        float4 v = x4[i];
        v.x *= s; v.y *= s; v.z *= s; v.w *= s;
        xs4[i] = v;
    }
}

// One wave per node (lane = feature), no LDS, 8-edge unroll.
// agg[node] = rsqrt(max(in_deg,1)) * sum_{s in N(node)} xs[s]
__global__ __launch_bounds__(256) void gather_kernel(
    const float* __restrict__ xs, const int* __restrict__ col,
    const int* __restrict__ curs, const int* __restrict__ cd,
    float* __restrict__ agg, int n) {
    int lane = threadIdx.x & 63;
    int node = (blockIdx.x * 256 + threadIdx.x) >> 6;
    if (node >= n) return;
    node = __builtin_amdgcn_readfirstlane(node);   // wave-uniform -> scalar loads

    int beg = (node > 0) ? curs[node - 1] : 0;
    int end = curs[node];

    float acc = 0.0f;
    int j = beg;
    for (; j + 8 <= end; j += 8) {
        int s0 = col[j + 0], s1 = col[j + 1], s2 = col[j + 2], s3 = col[j + 3];
        int s4 = col[j + 4], s5 = col[j + 5], s6 = col[j + 6], s7 = col[j + 7];
        float v0 = xs[(long)s0 * 64 + lane];
        float v1 = xs[(long)s1 * 64 + lane];
        float v2 = xs[(long)s2 * 64 + lane];
        float v3 = xs[(long)s3 * 64 + lane];
        float v4 = xs[(long)s4 * 64 + lane];
        float v5 = xs[(long)s5 * 64 + lane];
        float v6 = xs[(long)s6 * 64 + lane];
        float v7 = xs[(long)s7 * 64 + lane];
        acc += ((v0 + v1) + (v2 + v3)) + ((v4 + v5) + (v6 + v7));
    }
    for (; j < end; ++j) acc += xs[(long)col[j] * 64 + lane];

    float nd = rsqrtf((float)max(cd[node], 1));
    agg[(long)node * 64 + lane] = acc * nd;
}

// out[row][lane] = agg[row][:]@W[:,lane] + x[row][:]@Wr[:,lane] + (b+br)[lane]
// One wave per row (lane = output feature), weights in LDS, shfl broadcast.
__global__ __launch_bounds__(256) void out_kernel(
    const float* __restrict__ x, const float* __restrict__ agg,
    const float* __restrict__ W, const float* __restrict__ b,
    const float* __restrict__ Wr, const float* __restrict__ br,
    float* __restrict__ out, int n) {
    __shared__ float sW[4096];
    __shared__ float sWr[4096];
    for (int i = threadIdx.x; i < 4096; i += 256) {
        sW[i]  = W[i];
        sWr[i] = Wr[i];
    }
    __syncthreads();
    int lane = threadIdx.x & 63;
    int wid    = (blockIdx.x * blockDim.x + threadIdx.x) >> 6;
    int nwaves = (gridDim.x * blockDim.x) >> 6;
    float bias = b[lane] + br[lane];
    for (int row = wid; row < n; row += nwaves) {
        float a_own = agg[(long)row * 64 + lane];
        float x_own = x[(long)row * 64 + lane];
        float acc = bias;
        #pragma unroll
        for (int k = 0; k < 64; ++k) {
            float av = __shfl(a_own, k);
            float xv = __shfl(x_own, k);
            acc += av * sW[k * 64 + lane] + xv * sWr[k * 64 + lane];
        }
        out[(long)row * 64 + lane] = acc;
    }
}

extern "C" void kernel_launch(void* const* d_in, const int* in_sizes, int n_in,
                              void* d_out, int out_size, void* d_ws, size_t ws_size,
                              hipStream_t stream) {
    const float* x   = (const float*)d_in[0];
    const int*   src = (const int*)d_in[1];
    const int*   dst = (const int*)d_in[2];
    const float* W   = (const float*)d_in[3];
    const float* b   = (const float*)d_in[4];
    const float* Wr  = (const float*)d_in[5];
    const float* br  = (const float*)d_in[6];
    float* out = (float*)d_out;

    const int n = in_sizes[0] / 64;   // 50000
    const int e = in_sizes[1];        // 800000
    const int nblk = (n + 255) / 256; // 196

    int*   cs   = (int*)d_ws;          // n
    int*   cd   = cs + n;              // n
    int*   curs = cd + n;              // n
    int*   part = curs + n;            // 256
    int*   col  = part + 256;          // e
    float* xs   = (float*)(col + e);   // n*64
    float* agg  = xs + (size_t)n * 64; // n*64

    hipMemsetAsync(cs, 0, (size_t)n * 2 * sizeof(int), stream);

    hist_kernel<<<(e / 4 + 255) / 256, 256, 0, stream>>>(src, dst, cs, cd, e);

    partial_kernel<<<nblk, 256, 0, stream>>>(cd, part, n);
    scan_part_kernel<<<1, 256, 0, stream>>>(part, nblk);
    scan_final_kernel<<<nblk, 256, 0, stream>>>(cd, part, curs, n);

    scatter_kernel<<<(e + 255) / 256, 256, 0, stream>>>(src, dst, curs, col, e);

    prescale_kernel<<<(n * 16 + 255) / 256, 256, 0, stream>>>(
        (const float4*)x, cs, (float4*)xs, n * 16);

    gather_kernel<<<(n * 64 + 255) / 256, 256, 0, stream>>>(
        xs, col, curs, cd, agg, n);

    out_kernel<<<2048, 256, 0, stream>>>(x, agg, W, b, Wr, br, out, n);
}

// Round 5
// 203.487 us; speedup vs baseline: 2.8677x; 1.2354x over previous
//
#include <hip/hip_runtime.h>

// ---------------------------------------------------------------------------
// GraphConv (DGL norm='both') + residual linear:
//   out = (D_dst^-1/2 * A^T * (D_src^-1/2 * x)) @ W + x @ Wr + (b + br)
// Round 5: float4 gather (4 edges / dwordx4), epilogue GEMM with weight
// columns held in VGPRs (static unroll) + LDS row staging.
// ---------------------------------------------------------------------------

__global__ void hist_kernel(const int* __restrict__ src, const int* __restrict__ dst,
                            int* __restrict__ cs, int* __restrict__ cd, int e) {
    int i = blockIdx.x * blockDim.x + threadIdx.x;
    int e4 = e >> 2;
    if (i < e4) {
        int4 s = ((const int4*)src)[i];
        int4 d = ((const int4*)dst)[i];
        atomicAdd(&cs[s.x], 1); atomicAdd(&cs[s.y], 1);
        atomicAdd(&cs[s.z], 1); atomicAdd(&cs[s.w], 1);
        atomicAdd(&cd[d.x], 1); atomicAdd(&cd[d.y], 1);
        atomicAdd(&cd[d.z], 1); atomicAdd(&cd[d.w], 1);
    }
    int tail = e & 3;
    if (i < tail) {
        int j = (e & ~3) + i;
        atomicAdd(&cs[src[j]], 1);
        atomicAdd(&cd[dst[j]], 1);
    }
}

// Scan phase A: per-block (256-wide) partial sums of cd.
__global__ void partial_kernel(const int* __restrict__ cnt, int* __restrict__ part, int n) {
    __shared__ int sm[256];
    int i = blockIdx.x * 256 + threadIdx.x;
    sm[threadIdx.x] = (i < n) ? cnt[i] : 0;
    __syncthreads();
    for (int s = 128; s > 0; s >>= 1) {
        if (threadIdx.x < s) sm[threadIdx.x] += sm[threadIdx.x + s];
        __syncthreads();
    }
    if (threadIdx.x == 0) part[blockIdx.x] = sm[0];
}

// Scan phase B: single-block exclusive scan of the partials (nb <= 256).
__global__ void scan_part_kernel(int* __restrict__ part, int nb) {
    __shared__ int sm[256];
    int t = threadIdx.x;
    int v = (t < nb) ? part[t] : 0;
    sm[t] = v;
    __syncthreads();
    for (int d = 1; d < 256; d <<= 1) {
        int add = (t >= d) ? sm[t - d] : 0;
        __syncthreads();
        sm[t] += add;
        __syncthreads();
    }
    if (t < nb) part[t] = sm[t] - v;   // exclusive
}

// Scan phase C: local exclusive scan + block offset -> cursor (= excl prefix).
__global__ void scan_final_kernel(const int* __restrict__ cnt, const int* __restrict__ part,
                                  int* __restrict__ curs, int n) {
    __shared__ int sm[256];
    int t = threadIdx.x;
    int i = blockIdx.x * 256 + t;
    int v = (i < n) ? cnt[i] : 0;
    sm[t] = v;
    __syncthreads();
    for (int d = 1; d < 256; d <<= 1) {
        int add = (t >= d) ? sm[t - d] : 0;
        __syncthreads();
        sm[t] += add;
        __syncthreads();
    }
    if (i < n) curs[i] = sm[t] - v + part[blockIdx.x];
}

// Scatter edge sources into CSR col array. After this, curs[i] = row-end of i
// (inclusive prefix), so row i spans [curs[i-1], curs[i]).
__global__ void scatter_kernel(const int* __restrict__ src, const int* __restrict__ dst,
                               int* __restrict__ curs, int* __restrict__ col, int e) {
    int i = blockIdx.x * blockDim.x + threadIdx.x;
    if (i < e) {
        int p = atomicAdd(&curs[dst[i]], 1);
        col[p] = src[i];
    }
}

// xs = x * rsqrt(max(out_deg,1)), float4-vectorized.
__global__ void prescale_kernel(const float4* __restrict__ x4, const int* __restrict__ cs,
                                float4* __restrict__ xs4, int n16) {
    int i = blockIdx.x * blockDim.x + threadIdx.x;
    if (i < n16) {
        float s = rsqrtf((float)max(cs[i >> 4], 1));
        float4 v = x4[i];
        v.x *= s; v.y *= s; v.z *= s; v.w *= s;
        xs4[i] = v;
    }
}

// One wave per node. Lane = (edge-slot g = lane>>4) x (feature-quad q = lane&15).
// Each 4-edge group loads rows as dwordx4; cross-group shfl reduce at the end.
// agg[node] = rsqrt(max(in_deg,1)) * sum_{s in N(node)} xs[s]
__global__ __launch_bounds__(256) void gather_kernel(
    const float4* __restrict__ xs4, const int* __restrict__ col,
    const int* __restrict__ curs, const int* __restrict__ cd,
    float4* __restrict__ agg4, int n) {
    int lane = threadIdx.x & 63;
    int node = (blockIdx.x * 256 + threadIdx.x) >> 6;
    if (node >= n) return;
    node = __builtin_amdgcn_readfirstlane(node);   // wave-uniform -> scalar loads

    int beg = (node > 0) ? curs[node - 1] : 0;
    int end = curs[node];
    int g = lane >> 4;   // edge sub-slot 0..3
    int q = lane & 15;   // feature quad 0..15

    float4 acc = make_float4(0.f, 0.f, 0.f, 0.f);
    int j = beg;
    for (; j + 8 <= end; j += 8) {          // 8 edges: two 16B loads in flight
        int s0 = col[j + g];
        int s1 = col[j + 4 + g];
        float4 v0 = xs4[(long)s0 * 16 + q];
        float4 v1 = xs4[(long)s1 * 16 + q];
        acc.x += v0.x + v1.x;
        acc.y += v0.y + v1.y;
        acc.z += v0.z + v1.z;
        acc.w += v0.w + v1.w;
    }
    for (; j < end; j += 4) {               // predicated 4-edge tail
        int jj = j + g;
        int s   = (jj < end) ? col[jj] : node;   // safe dummy index
        float m = (jj < end) ? 1.f : 0.f;
        float4 v = xs4[(long)s * 16 + q];
        acc.x += v.x * m;
        acc.y += v.y * m;
        acc.z += v.z * m;
        acc.w += v.w * m;
    }

    // reduce across the 4 edge-slots (lanes q, q+16, q+32, q+48)
    acc.x += __shfl_down(acc.x, 32);
    acc.y += __shfl_down(acc.y, 32);
    acc.z += __shfl_down(acc.z, 32);
    acc.w += __shfl_down(acc.w, 32);
    acc.x += __shfl_down(acc.x, 16);
    acc.y += __shfl_down(acc.y, 16);
    acc.z += __shfl_down(acc.z, 16);
    acc.w += __shfl_down(acc.w, 16);

    float nd = rsqrtf((float)max(cd[node], 1));
    if (lane < 16) {
        acc.x *= nd; acc.y *= nd; acc.z *= nd; acc.w *= nd;
        agg4[(long)node * 16 + q] = acc;
    }
}

// out[r][c] = agg[r][:]@W[:,c] + x[r][:]@Wr[:,c] + (b+br)[c]
// Lane c holds W[:,c], Wr[:,c] in VGPRs (static unroll); rows staged in LDS;
// per row: 32 broadcast ds_read_b128 + 128 FMA.
#define OR 32
__global__ __launch_bounds__(256) void out_kernel(
    const float4* __restrict__ agg4, const float4* __restrict__ x4,
    const float* __restrict__ W, const float* __restrict__ b,
    const float* __restrict__ Wr, const float* __restrict__ br,
    float* __restrict__ out, int n) {
    __shared__ float4 sA[OR * 16];
    __shared__ float4 sX[OR * 16];
    int t = threadIdx.x;
    int c = t & 63;
    int base = blockIdx.x * OR;

    float4 wA[16], wR[16];
    #pragma unroll
    for (int q = 0; q < 16; ++q) {
        wA[q].x = W[(4 * q + 0) * 64 + c];
        wA[q].y = W[(4 * q + 1) * 64 + c];
        wA[q].z = W[(4 * q + 2) * 64 + c];
        wA[q].w = W[(4 * q + 3) * 64 + c];
        wR[q].x = Wr[(4 * q + 0) * 64 + c];
        wR[q].y = Wr[(4 * q + 1) * 64 + c];
        wR[q].z = Wr[(4 * q + 2) * 64 + c];
        wR[q].w = Wr[(4 * q + 3) * 64 + c];
    }

    #pragma unroll
    for (int i = 0; i < 2; ++i) {          // stage 32 rows of A and X
        int qi = t + 256 * i;              // 0..511
        int row = base + (qi >> 4);
        float4 z = make_float4(0.f, 0.f, 0.f, 0.f);
        sA[qi] = (row < n) ? agg4[(long)row * 16 + (qi & 15)] : z;
        sX[qi] = (row < n) ? x4[(long)row * 16 + (qi & 15)] : z;
    }
    __syncthreads();

    int w = t >> 6;
    float bias = b[c] + br[c];
    for (int r = w * 8; r < w * 8 + 8; ++r) {
        float a0 = 0.f, a1 = 0.f, r0 = 0.f, r1 = 0.f;
        #pragma unroll
        for (int q = 0; q < 16; q += 2) {
            float4 av0 = sA[r * 16 + q];
            float4 av1 = sA[r * 16 + q + 1];
            float4 xv0 = sX[r * 16 + q];
            float4 xv1 = sX[r * 16 + q + 1];
            a0 += av0.x * wA[q].x + av0.y * wA[q].y + av0.z * wA[q].z + av0.w * wA[q].w;
            a1 += av1.x * wA[q + 1].x + av1.y * wA[q + 1].y + av1.z * wA[q + 1].z + av1.w * wA[q + 1].w;
            r0 += xv0.x * wR[q].x + xv0.y * wR[q].y + xv0.z * wR[q].z + xv0.w * wR[q].w;
            r1 += xv1.x * wR[q + 1].x + xv1.y * wR[q + 1].y + xv1.z * wR[q + 1].z + xv1.w * wR[q + 1].w;
        }
        int grow = base + r;
        if (grow < n) out[(long)grow * 64 + c] = (a0 + a1) + (r0 + r1) + bias;
    }
}

extern "C" void kernel_launch(void* const* d_in, const int* in_sizes, int n_in,
                              void* d_out, int out_size, void* d_ws, size_t ws_size,
                              hipStream_t stream) {
    const float* x   = (const float*)d_in[0];
    const int*   src = (const int*)d_in[1];
    const int*   dst = (const int*)d_in[2];
    const float* W   = (const float*)d_in[3];
    const float* b   = (const float*)d_in[4];
    const float* Wr  = (const float*)d_in[5];
    const float* br  = (const float*)d_in[6];
    float* out = (float*)d_out;

    const int n = in_sizes[0] / 64;   // 50000
    const int e = in_sizes[1];        // 800000
    const int nblk = (n + 255) / 256; // 196

    int*   cs   = (int*)d_ws;          // n
    int*   cd   = cs + n;              // n
    int*   curs = cd + n;              // n
    int*   part = curs + n;            // 256
    int*   col  = part + 256;          // e
    float* xs   = (float*)(col + e);   // n*64
    float* agg  = xs + (size_t)n * 64; // n*64

    hipMemsetAsync(cs, 0, (size_t)n * 2 * sizeof(int), stream);

    hist_kernel<<<(e / 4 + 255) / 256, 256, 0, stream>>>(src, dst, cs, cd, e);

    partial_kernel<<<nblk, 256, 0, stream>>>(cd, part, n);
    scan_part_kernel<<<1, 256, 0, stream>>>(part, nblk);
    scan_final_kernel<<<nblk, 256, 0, stream>>>(cd, part, curs, n);

    scatter_kernel<<<(e + 255) / 256, 256, 0, stream>>>(src, dst, curs, col, e);

    prescale_kernel<<<(n * 16 + 255) / 256, 256, 0, stream>>>(
        (const float4*)x, cs, (float4*)xs, n * 16);

    gather_kernel<<<(n * 64 + 255) / 256, 256, 0, stream>>>(
        (const float4*)xs, col, curs, cd, (float4*)agg, n);

    out_kernel<<<(n + OR - 1) / OR, 256, 0, stream>>>(
        (const float4*)agg, (const float4*)x, W, b, Wr, br, out, n);
}

// Round 6
// 188.119 us; speedup vs baseline: 3.1020x; 1.0817x over previous
//
#include <hip/hip_runtime.h>

// ---------------------------------------------------------------------------
// GraphConv (DGL norm='both') + residual linear:
//   out = (D_dst^-1/2 * A^T * (D_src^-1/2 * x)) @ W + x @ Wr + (b + br)
// Round 6: replicated-counter histogram (R=8) with rank capture ->
// atomic-free scatter; bucket-scan CSR; float4 gather; VGPR-weight epilogue.
// ---------------------------------------------------------------------------

#define R 8

// Histogram with R-way replicated counters. For dst we also capture each
// edge's rank within its (dst, replica) bucket -> scatter needs no atomics.
__global__ void hist_kernel(const int* __restrict__ src, const int* __restrict__ dst,
                            int* __restrict__ csR, int* __restrict__ cdB,
                            unsigned short* __restrict__ rank, int e, int n) {
    int i = blockIdx.x * blockDim.x + threadIdx.x;
    int r = threadIdx.x & (R - 1);
    int e4 = e >> 2;
    if (i < e4) {
        int4 s = ((const int4*)src)[i];
        int4 d = ((const int4*)dst)[i];
        atomicAdd(&csR[r * n + s.x], 1);
        atomicAdd(&csR[r * n + s.y], 1);
        atomicAdd(&csR[r * n + s.z], 1);
        atomicAdd(&csR[r * n + s.w], 1);
        int rk0 = atomicAdd(&cdB[d.x * R + r], 1);
        int rk1 = atomicAdd(&cdB[d.y * R + r], 1);
        int rk2 = atomicAdd(&cdB[d.z * R + r], 1);
        int rk3 = atomicAdd(&cdB[d.w * R + r], 1);
        rank[4 * i + 0] = (unsigned short)rk0;
        rank[4 * i + 1] = (unsigned short)rk1;
        rank[4 * i + 2] = (unsigned short)rk2;
        rank[4 * i + 3] = (unsigned short)rk3;
    }
    int tail = e & 3;
    if (i < tail) {
        int j = (e & ~3) + i;
        atomicAdd(&csR[r * n + src[j]], 1);
        rank[j] = (unsigned short)atomicAdd(&cdB[dst[j] * R + r], 1);
    }
}

// ns[i] = rsqrt(max(out_deg,1)); out_deg = sum over replicas.
__global__ void norm_src_kernel(const int* __restrict__ csR, float* __restrict__ ns, int n) {
    int i = blockIdx.x * blockDim.x + threadIdx.x;
    if (i < n) {
        int c = 0;
        #pragma unroll
        for (int r = 0; r < R; ++r) c += csR[r * n + i];
        ns[i] = rsqrtf((float)max(c, 1));
    }
}

// Scan phase A over m bucket counts: 4096 elems/block (256 thr x 16).
__global__ void partial_kernel(const int* __restrict__ cnt, int* __restrict__ part, int m) {
    __shared__ int sm[256];
    int t = threadIdx.x;
    int base = blockIdx.x * 4096 + t * 16;
    int s = 0;
    if (base + 16 <= m) {
        const int4* p = (const int4*)(cnt + base);
        #pragma unroll
        for (int k = 0; k < 4; ++k) { int4 v = p[k]; s += v.x + v.y + v.z + v.w; }
    } else {
        for (int k = 0; k < 16; ++k) if (base + k < m) s += cnt[base + k];
    }
    sm[t] = s;
    __syncthreads();
    for (int st = 128; st > 0; st >>= 1) {
        if (t < st) sm[t] += sm[t + st];
        __syncthreads();
    }
    if (t == 0) part[blockIdx.x] = sm[0];
}

// Scan phase B: single-block exclusive scan of the partials (nb <= 256).
__global__ void scan_part_kernel(int* __restrict__ part, int nb) {
    __shared__ int sm[256];
    int t = threadIdx.x;
    int v = (t < nb) ? part[t] : 0;
    sm[t] = v;
    __syncthreads();
    for (int d = 1; d < 256; d <<= 1) {
        int add = (t >= d) ? sm[t - d] : 0;
        __syncthreads();
        sm[t] += add;
        __syncthreads();
    }
    if (t < nb) part[t] = sm[t] - v;   // exclusive
}

// Scan phase C: in-place exclusive scan of bucket counts -> bucket offsets.
__global__ void scan_final_kernel(int* __restrict__ cnt, const int* __restrict__ part, int m) {
    __shared__ int sm[256];
    int t = threadIdx.x;
    int base = blockIdx.x * 4096 + t * 16;
    int v[16];
    #pragma unroll
    for (int k = 0; k < 16; ++k) v[k] = (base + k < m) ? cnt[base + k] : 0;
    int s = 0;
    #pragma unroll
    for (int k = 0; k < 16; ++k) { int x = v[k]; v[k] = s; s += x; }
    sm[t] = s;
    __syncthreads();
    for (int d = 1; d < 256; d <<= 1) {
        int add = (t >= d) ? sm[t - d] : 0;
        __syncthreads();
        sm[t] += add;
        __syncthreads();
    }
    int tb = sm[t] - s + part[blockIdx.x];
    #pragma unroll
    for (int k = 0; k < 16; ++k)
        if (base + k < m) cnt[base + k] = v[k] + tb;
}

// Atomic-free scatter: slot = roff[dst*R + r] + rank.  (r mapping identical
// to hist_kernel's.)
__global__ void scatter_kernel(const int* __restrict__ src, const int* __restrict__ dst,
                               const int* __restrict__ roff,
                               const unsigned short* __restrict__ rank,
                               int* __restrict__ col, int e) {
    int i = blockIdx.x * blockDim.x + threadIdx.x;
    int r = threadIdx.x & (R - 1);
    int e4 = e >> 2;
    if (i < e4) {
        int4 s = ((const int4*)src)[i];
        int4 d = ((const int4*)dst)[i];
        ushort4 rk = ((const ushort4*)rank)[i];
        col[roff[d.x * R + r] + rk.x] = s.x;
        col[roff[d.y * R + r] + rk.y] = s.y;
        col[roff[d.z * R + r] + rk.z] = s.z;
        col[roff[d.w * R + r] + rk.w] = s.w;
    }
    int tail = e & 3;
    if (i < tail) {
        int j = (e & ~3) + i;
        col[roff[dst[j] * R + r] + rank[j]] = src[j];
    }
}

// xs = x * ns[node], float4-vectorized.
__global__ void prescale_kernel(const float4* __restrict__ x4, const float* __restrict__ ns,
                                float4* __restrict__ xs4, int n16) {
    int i = blockIdx.x * blockDim.x + threadIdx.x;
    if (i < n16) {
        float s = ns[i >> 4];
        float4 v = x4[i];
        v.x *= s; v.y *= s; v.z *= s; v.w *= s;
        xs4[i] = v;
    }
}

// One wave per node. Lane = (edge-slot g = lane>>4) x (feature-quad q = lane&15).
// agg[node] = rsqrt(max(in_deg,1)) * sum_{s in N(node)} xs[s]; in_deg = end-beg.
__global__ __launch_bounds__(256) void gather_kernel(
    const float4* __restrict__ xs4, const int* __restrict__ col,
    const int* __restrict__ roff,
    float4* __restrict__ agg4, int n, int e) {
    int lane = threadIdx.x & 63;
    int node = (blockIdx.x * 256 + threadIdx.x) >> 6;
    if (node >= n) return;
    node = __builtin_amdgcn_readfirstlane(node);   // wave-uniform -> scalar loads

    int beg = roff[node * R];
    int end = (node + 1 < n) ? roff[(node + 1) * R] : e;
    int g = lane >> 4;   // edge sub-slot 0..3
    int q = lane & 15;   // feature quad 0..15

    float4 acc = make_float4(0.f, 0.f, 0.f, 0.f);
    int j = beg;
    for (; j + 8 <= end; j += 8) {          // 8 edges: two 16B loads in flight
        int s0 = col[j + g];
        int s1 = col[j + 4 + g];
        float4 v0 = xs4[(long)s0 * 16 + q];
        float4 v1 = xs4[(long)s1 * 16 + q];
        acc.x += v0.x + v1.x;
        acc.y += v0.y + v1.y;
        acc.z += v0.z + v1.z;
        acc.w += v0.w + v1.w;
    }
    for (; j < end; j += 4) {               // predicated 4-edge tail
        int jj = j + g;
        int s   = (jj < end) ? col[jj] : node;   // safe dummy index
        float m = (jj < end) ? 1.f : 0.f;
        float4 v = xs4[(long)s * 16 + q];
        acc.x += v.x * m;
        acc.y += v.y * m;
        acc.z += v.z * m;
        acc.w += v.w * m;
    }

    // reduce across the 4 edge-slots (lanes q, q+16, q+32, q+48)
    acc.x += __shfl_down(acc.x, 32);
    acc.y += __shfl_down(acc.y, 32);
    acc.z += __shfl_down(acc.z, 32);
    acc.w += __shfl_down(acc.w, 32);
    acc.x += __shfl_down(acc.x, 16);
    acc.y += __shfl_down(acc.y, 16);
    acc.z += __shfl_down(acc.z, 16);
    acc.w += __shfl_down(acc.w, 16);

    float nd = rsqrtf((float)max(end - beg, 1));
    if (lane < 16) {
        acc.x *= nd; acc.y *= nd; acc.z *= nd; acc.w *= nd;
        agg4[(long)node * 16 + q] = acc;
    }
}

// out[r][c] = agg[r][:]@W[:,c] + x[r][:]@Wr[:,c] + (b+br)[c]
// Lane c holds W[:,c], Wr[:,c] in VGPRs (static unroll); rows staged in LDS.
#define OR 32
__global__ __launch_bounds__(256) void out_kernel(
    const float4* __restrict__ agg4, const float4* __restrict__ x4,
    const float* __restrict__ W, const float* __restrict__ b,
    const float* __restrict__ Wr, const float* __restrict__ br,
    float* __restrict__ out, int n) {
    __shared__ float4 sA[OR * 16];
    __shared__ float4 sX[OR * 16];
    int t = threadIdx.x;
    int c = t & 63;
    int base = blockIdx.x * OR;

    float4 wA[16], wR[16];
    #pragma unroll
    for (int q = 0; q < 16; ++q) {
        wA[q].x = W[(4 * q + 0) * 64 + c];
        wA[q].y = W[(4 * q + 1) * 64 + c];
        wA[q].z = W[(4 * q + 2) * 64 + c];
        wA[q].w = W[(4 * q + 3) * 64 + c];
        wR[q].x = Wr[(4 * q + 0) * 64 + c];
        wR[q].y = Wr[(4 * q + 1) * 64 + c];
        wR[q].z = Wr[(4 * q + 2) * 64 + c];
        wR[q].w = Wr[(4 * q + 3) * 64 + c];
    }

    #pragma unroll
    for (int i = 0; i < 2; ++i) {          // stage 32 rows of A and X
        int qi = t + 256 * i;              // 0..511
        int row = base + (qi >> 4);
        float4 z = make_float4(0.f, 0.f, 0.f, 0.f);
        sA[qi] = (row < n) ? agg4[(long)row * 16 + (qi & 15)] : z;
        sX[qi] = (row < n) ? x4[(long)row * 16 + (qi & 15)] : z;
    }
    __syncthreads();

    int w = t >> 6;
    float bias = b[c] + br[c];
    for (int r = w * 8; r < w * 8 + 8; ++r) {
        float a0 = 0.f, a1 = 0.f, r0 = 0.f, r1 = 0.f;
        #pragma unroll
        for (int q = 0; q < 16; q += 2) {
            float4 av0 = sA[r * 16 + q];
            float4 av1 = sA[r * 16 + q + 1];
            float4 xv0 = sX[r * 16 + q];
            float4 xv1 = sX[r * 16 + q + 1];
            a0 += av0.x * wA[q].x + av0.y * wA[q].y + av0.z * wA[q].z + av0.w * wA[q].w;
            a1 += av1.x * wA[q + 1].x + av1.y * wA[q + 1].y + av1.z * wA[q + 1].z + av1.w * wA[q + 1].w;
            r0 += xv0.x * wR[q].x + xv0.y * wR[q].y + xv0.z * wR[q].z + xv0.w * wR[q].w;
            r1 += xv1.x * wR[q + 1].x + xv1.y * wR[q + 1].y + xv1.z * wR[q + 1].z + xv1.w * wR[q + 1].w;
        }
        int grow = base + r;
        if (grow < n) out[(long)grow * 64 + c] = (a0 + a1) + (r0 + r1) + bias;
    }
}

extern "C" void kernel_launch(void* const* d_in, const int* in_sizes, int n_in,
                              void* d_out, int out_size, void* d_ws, size_t ws_size,
                              hipStream_t stream) {
    const float* x   = (const float*)d_in[0];
    const int*   src = (const int*)d_in[1];
    const int*   dst = (const int*)d_in[2];
    const float* W   = (const float*)d_in[3];
    const float* b   = (const float*)d_in[4];
    const float* Wr  = (const float*)d_in[5];
    const float* br  = (const float*)d_in[6];
    float* out = (float*)d_out;

    const int n = in_sizes[0] / 64;   // 50000
    const int e = in_sizes[1];        // 800000
    const int m = R * n;              // 400000 dst buckets
    const int nbs = (m + 4095) / 4096; // 98 scan blocks

    int*   csR  = (int*)d_ws;              // R*n
    int*   cdB  = csR + (size_t)R * n;     // R*n (in-place becomes roff)
    int*   part = cdB + (size_t)R * n;     // 256
    int*   col  = part + 256;              // e
    float* ns   = (float*)(col + e);       // n
    float* xs   = ns + n;                  // n*64
    float* agg  = xs + (size_t)n * 64;     // n*64
    unsigned short* rank = (unsigned short*)(agg + (size_t)n * 64); // e

    // zero only the replicated counters (csR and cdB are contiguous)
    hipMemsetAsync(csR, 0, (size_t)2 * R * n * sizeof(int), stream);

    hist_kernel<<<(e / 4 + 255) / 256, 256, 0, stream>>>(src, dst, csR, cdB, rank, e, n);

    norm_src_kernel<<<(n + 255) / 256, 256, 0, stream>>>(csR, ns, n);

    partial_kernel<<<nbs, 256, 0, stream>>>(cdB, part, m);
    scan_part_kernel<<<1, 256, 0, stream>>>(part, nbs);
    scan_final_kernel<<<nbs, 256, 0, stream>>>(cdB, part, m);

    scatter_kernel<<<(e / 4 + 255) / 256, 256, 0, stream>>>(src, dst, cdB, rank, col, e);

    prescale_kernel<<<(n * 16 + 255) / 256, 256, 0, stream>>>(
        (const float4*)x, ns, (float4*)xs, n * 16);

    gather_kernel<<<(n * 64 + 255) / 256, 256, 0, stream>>>(
        (const float4*)xs, col, cdB, (float4*)agg, n, e);

    out_kernel<<<(n + OR - 1) / OR, 256, 0, stream>>>(
        (const float4*)agg, (const float4*)x, W, b, Wr, br, out, n);
}

// Round 7
// 183.321 us; speedup vs baseline: 3.1832x; 1.0262x over previous
//
#include <hip/hip_runtime.h>

// ---------------------------------------------------------------------------
// GraphConv (DGL norm='both') + residual linear:
//   out = (D_dst^-1/2 * A^T * (D_src^-1/2 * x)) @ W + x @ Wr + (b + br)
// Round 7: max-TLP histogram (1 edge/thread) with rank capture -> atomic-free
// scatter; n-sized scan; float4 gather; VGPR-weight epilogue.
// ---------------------------------------------------------------------------

// 1 edge per thread: 2 atomics, maximal wave count to hide atomic latency.
__global__ void hist_kernel(const int* __restrict__ src, const int* __restrict__ dst,
                            int* __restrict__ cs, int* __restrict__ cd,
                            unsigned short* __restrict__ rank, int e) {
    int i = blockIdx.x * blockDim.x + threadIdx.x;
    if (i < e) {
        atomicAdd(&cs[src[i]], 1);
        rank[i] = (unsigned short)atomicAdd(&cd[dst[i]], 1);
    }
}

// ns[i] = rsqrt(max(out_deg,1))
__global__ void norm_src_kernel(const int* __restrict__ cs, float* __restrict__ ns, int n) {
    int i = blockIdx.x * blockDim.x + threadIdx.x;
    if (i < n) ns[i] = rsqrtf((float)max(cs[i], 1));
}

// Scan phase A over n counts: 4096 elems/block (256 thr x 16).
__global__ void partial_kernel(const int* __restrict__ cnt, int* __restrict__ part, int m) {
    __shared__ int sm[256];
    int t = threadIdx.x;
    int base = blockIdx.x * 4096 + t * 16;
    int s = 0;
    if (base + 16 <= m) {
        const int4* p = (const int4*)(cnt + base);
        #pragma unroll
        for (int k = 0; k < 4; ++k) { int4 v = p[k]; s += v.x + v.y + v.z + v.w; }
    } else {
        for (int k = 0; k < 16; ++k) if (base + k < m) s += cnt[base + k];
    }
    sm[t] = s;
    __syncthreads();
    for (int st = 128; st > 0; st >>= 1) {
        if (t < st) sm[t] += sm[t + st];
        __syncthreads();
    }
    if (t == 0) part[blockIdx.x] = sm[0];
}

// Scan phase B: single-block exclusive scan of the partials (nb <= 256).
__global__ void scan_part_kernel(int* __restrict__ part, int nb) {
    __shared__ int sm[256];
    int t = threadIdx.x;
    int v = (t < nb) ? part[t] : 0;
    sm[t] = v;
    __syncthreads();
    for (int d = 1; d < 256; d <<= 1) {
        int add = (t >= d) ? sm[t - d] : 0;
        __syncthreads();
        sm[t] += add;
        __syncthreads();
    }
    if (t < nb) part[t] = sm[t] - v;   // exclusive
}

// Scan phase C: exclusive scan of cd -> roff (n+1 entries, roff[n] = e).
__global__ void scan_final_kernel(const int* __restrict__ cnt, const int* __restrict__ part,
                                  int* __restrict__ roff, int m, int e) {
    __shared__ int sm[256];
    int t = threadIdx.x;
    int base = blockIdx.x * 4096 + t * 16;
    int v[16];
    #pragma unroll
    for (int k = 0; k < 16; ++k) v[k] = (base + k < m) ? cnt[base + k] : 0;
    int s = 0;
    #pragma unroll
    for (int k = 0; k < 16; ++k) { int x = v[k]; v[k] = s; s += x; }
    sm[t] = s;
    __syncthreads();
    for (int d = 1; d < 256; d <<= 1) {
        int add = (t >= d) ? sm[t - d] : 0;
        __syncthreads();
        sm[t] += add;
        __syncthreads();
    }
    int tb = sm[t] - s + part[blockIdx.x];
    #pragma unroll
    for (int k = 0; k < 16; ++k)
        if (base + k < m) roff[base + k] = v[k] + tb;
    if (base == 0 && t == 0) roff[m] = e;
}

// Atomic-free scatter: slot = roff[dst] + rank. 1 edge/thread for TLP.
__global__ void scatter_kernel(const int* __restrict__ src, const int* __restrict__ dst,
                               const int* __restrict__ roff,
                               const unsigned short* __restrict__ rank,
                               int* __restrict__ col, int e) {
    int i = blockIdx.x * blockDim.x + threadIdx.x;
    if (i < e) col[roff[dst[i]] + rank[i]] = src[i];
}

// xs = x * ns[node], float4-vectorized.
__global__ void prescale_kernel(const float4* __restrict__ x4, const float* __restrict__ ns,
                                float4* __restrict__ xs4, int n16) {
    int i = blockIdx.x * blockDim.x + threadIdx.x;
    if (i < n16) {
        float s = ns[i >> 4];
        float4 v = x4[i];
        v.x *= s; v.y *= s; v.z *= s; v.w *= s;
        xs4[i] = v;
    }
}

// One wave per node. Lane = (edge-slot g = lane>>4) x (feature-quad q = lane&15).
// agg[node] = rsqrt(max(in_deg,1)) * sum_{s in N(node)} xs[s]; in_deg = end-beg.
__global__ __launch_bounds__(256) void gather_kernel(
    const float4* __restrict__ xs4, const int* __restrict__ col,
    const int* __restrict__ roff,
    float4* __restrict__ agg4, int n) {
    int lane = threadIdx.x & 63;
    int node = (blockIdx.x * 256 + threadIdx.x) >> 6;
    if (node >= n) return;
    node = __builtin_amdgcn_readfirstlane(node);   // wave-uniform -> scalar loads

    int beg = roff[node];
    int end = roff[node + 1];
    int g = lane >> 4;   // edge sub-slot 0..3
    int q = lane & 15;   // feature quad 0..15

    float4 acc = make_float4(0.f, 0.f, 0.f, 0.f);
    int j = beg;
    for (; j + 8 <= end; j += 8) {          // 8 edges: two 16B loads in flight
        int s0 = col[j + g];
        int s1 = col[j + 4 + g];
        float4 v0 = xs4[(long)s0 * 16 + q];
        float4 v1 = xs4[(long)s1 * 16 + q];
        acc.x += v0.x + v1.x;
        acc.y += v0.y + v1.y;
        acc.z += v0.z + v1.z;
        acc.w += v0.w + v1.w;
    }
    for (; j < end; j += 4) {               // predicated 4-edge tail
        int jj = j + g;
        int s   = (jj < end) ? col[jj] : node;   // safe dummy index
        float m = (jj < end) ? 1.f : 0.f;
        float4 v = xs4[(long)s * 16 + q];
        acc.x += v.x * m;
        acc.y += v.y * m;
        acc.z += v.z * m;
        acc.w += v.w * m;
    }

    // reduce across the 4 edge-slots (lanes q, q+16, q+32, q+48)
    acc.x += __shfl_down(acc.x, 32);
    acc.y += __shfl_down(acc.y, 32);
    acc.z += __shfl_down(acc.z, 32);
    acc.w += __shfl_down(acc.w, 32);
    acc.x += __shfl_down(acc.x, 16);
    acc.y += __shfl_down(acc.y, 16);
    acc.z += __shfl_down(acc.z, 16);
    acc.w += __shfl_down(acc.w, 16);

    float nd = rsqrtf((float)max(end - beg, 1));
    if (lane < 16) {
        acc.x *= nd; acc.y *= nd; acc.z *= nd; acc.w *= nd;
        agg4[(long)node * 16 + q] = acc;
    }
}

// out[r][c] = agg[r][:]@W[:,c] + x[r][:]@Wr[:,c] + (b+br)[c]
// Lane c holds W[:,c], Wr[:,c] in VGPRs (static unroll); rows staged in LDS.
#define OR 32
__global__ __launch_bounds__(256) void out_kernel(
    const float4* __restrict__ agg4, const float4* __restrict__ x4,
    const float* __restrict__ W, const float* __restrict__ b,
    const float* __restrict__ Wr, const float* __restrict__ br,
    float* __restrict__ out, int n) {
    __shared__ float4 sA[OR * 16];
    __shared__ float4 sX[OR * 16];
    int t = threadIdx.x;
    int c = t & 63;
    int base = blockIdx.x * OR;

    float4 wA[16], wR[16];
    #pragma unroll
    for (int q = 0; q < 16; ++q) {
        wA[q].x = W[(4 * q + 0) * 64 + c];
        wA[q].y = W[(4 * q + 1) * 64 + c];
        wA[q].z = W[(4 * q + 2) * 64 + c];
        wA[q].w = W[(4 * q + 3) * 64 + c];
        wR[q].x = Wr[(4 * q + 0) * 64 + c];
        wR[q].y = Wr[(4 * q + 1) * 64 + c];
        wR[q].z = Wr[(4 * q + 2) * 64 + c];
        wR[q].w = Wr[(4 * q + 3) * 64 + c];
    }

    #pragma unroll
    for (int i = 0; i < 2; ++i) {          // stage 32 rows of A and X
        int qi = t + 256 * i;              // 0..511
        int row = base + (qi >> 4);
        float4 z = make_float4(0.f, 0.f, 0.f, 0.f);
        sA[qi] = (row < n) ? agg4[(long)row * 16 + (qi & 15)] : z;
        sX[qi] = (row < n) ? x4[(long)row * 16 + (qi & 15)] : z;
    }
    __syncthreads();

    int w = t >> 6;
    float bias = b[c] + br[c];
    for (int r = w * 8; r < w * 8 + 8; ++r) {
        float a0 = 0.f, a1 = 0.f, r0 = 0.f, r1 = 0.f;
        #pragma unroll
        for (int q = 0; q < 16; q += 2) {
            float4 av0 = sA[r * 16 + q];
            float4 av1 = sA[r * 16 + q + 1];
            float4 xv0 = sX[r * 16 + q];
            float4 xv1 = sX[r * 16 + q + 1];
            a0 += av0.x * wA[q].x + av0.y * wA[q].y + av0.z * wA[q].z + av0.w * wA[q].w;
            a1 += av1.x * wA[q + 1].x + av1.y * wA[q + 1].y + av1.z * wA[q + 1].z + av1.w * wA[q + 1].w;
            r0 += xv0.x * wR[q].x + xv0.y * wR[q].y + xv0.z * wR[q].z + xv0.w * wR[q].w;
            r1 += xv1.x * wR[q + 1].x + xv1.y * wR[q + 1].y + xv1.z * wR[q + 1].z + xv1.w * wR[q + 1].w;
        }
        int grow = base + r;
        if (grow < n) out[(long)grow * 64 + c] = (a0 + a1) + (r0 + r1) + bias;
    }
}

extern "C" void kernel_launch(void* const* d_in, const int* in_sizes, int n_in,
                              void* d_out, int out_size, void* d_ws, size_t ws_size,
                              hipStream_t stream) {
    const float* x   = (const float*)d_in[0];
    const int*   src = (const int*)d_in[1];
    const int*   dst = (const int*)d_in[2];
    const float* W   = (const float*)d_in[3];
    const float* b   = (const float*)d_in[4];
    const float* Wr  = (const float*)d_in[5];
    const float* br  = (const float*)d_in[6];
    float* out = (float*)d_out;

    const int n = in_sizes[0] / 64;    // 50000
    const int e = in_sizes[1];         // 800000
    const int nbs = (n + 4095) / 4096; // 13 scan blocks

    int*   cs   = (int*)d_ws;              // n
    int*   cd   = cs + n;                  // n
    int*   roff = cd + n;                  // n+1
    int*   part = roff + n + 1;            // 256
    int*   col  = part + 256;              // e
    float* ns   = (float*)(col + e);       // n
    float* xs   = ns + n;                  // n*64
    float* agg  = xs + (size_t)n * 64;     // n*64
    unsigned short* rank = (unsigned short*)(agg + (size_t)n * 64); // e

    // zero only the counters
    hipMemsetAsync(cs, 0, (size_t)2 * n * sizeof(int), stream);

    hist_kernel<<<(e + 255) / 256, 256, 0, stream>>>(src, dst, cs, cd, rank, e);

    norm_src_kernel<<<(n + 255) / 256, 256, 0, stream>>>(cs, ns, n);

    partial_kernel<<<nbs, 256, 0, stream>>>(cd, part, n);
    scan_part_kernel<<<1, 256, 0, stream>>>(part, nbs);
    scan_final_kernel<<<nbs, 256, 0, stream>>>(cd, part, roff, n, e);

    scatter_kernel<<<(e + 255) / 256, 256, 0, stream>>>(src, dst, roff, rank, col, e);

    prescale_kernel<<<(n * 16 + 255) / 256, 256, 0, stream>>>(
        (const float4*)x, ns, (float4*)xs, n * 16);

    gather_kernel<<<(n * 64 + 255) / 256, 256, 0, stream>>>(
        (const float4*)xs, col, roff, (float4*)agg, n);

    out_kernel<<<(n + OR - 1) / OR, 256, 0, stream>>>(
        (const float4*)agg, (const float4*)x, W, b, Wr, br, out, n);
}